// Round 1
// baseline (255.861 us; speedup 1.0000x reference)
//
#include <hip/hip_runtime.h>

#define B_ 8
#define CIN_ 256
#define COUT_ 256
#define H_ 64
#define W_ 64

typedef short short8_t __attribute__((ext_vector_type(8)));
typedef float float4_t __attribute__((ext_vector_type(4)));

__device__ __forceinline__ unsigned short f2bf(float f) {
    union { float f; unsigned u; } v; v.f = f;
    unsigned u = v.u;
    // round-to-nearest-even
    unsigned r = (u + 0x7fffu + ((u >> 16) & 1u)) >> 16;
    return (unsigned short)r;
}

// Kernel 1: modulate + demodulate, write bf16 weights in fragment-ready layout:
// dwA[b][tap][ci_oct(32)][co(256)][ci8(8)]  (ci_oct = ci>>3)
__global__ __launch_bounds__(256) void k_modulate(
    const float* __restrict__ weight, const float* __restrict__ style,
    unsigned short* __restrict__ dwA)
{
    const int co = blockIdx.x;
    const int b  = blockIdx.y;
    const int ci = threadIdx.x;

    const float s = style[b * CIN_ + ci];
    float wv[9];
    const float* wp = weight + ((size_t)co * CIN_ + ci) * 9;
    float ss = 0.f;
#pragma unroll
    for (int k = 0; k < 9; ++k) { wv[k] = wp[k]; ss += wv[k] * wv[k]; }
    float part = s * s * ss;

    // wave64 reduce then cross-wave via LDS
#pragma unroll
    for (int off = 32; off > 0; off >>= 1)
        part += __shfl_down(part, off, 64);
    __shared__ float red[4];
    const int lane = threadIdx.x & 63, wid = threadIdx.x >> 6;
    if (lane == 0) red[wid] = part;
    __syncthreads();
    const float total = red[0] + red[1] + red[2] + red[3];
    const float inv = 1.0f / sqrtf(total + 1e-8f);
    const float sv = s * inv;

#pragma unroll
    for (int tap = 0; tap < 9; ++tap) {
        float val = wv[tap] * sv;
        size_t idx = (((size_t)(b * 9 + tap) * 32 + (ci >> 3)) * 256 + co) * 8 + (ci & 7);
        dwA[idx] = f2bf(val);
    }
}

// Kernel 2: conv as 9 shifted GEMMs with bf16 MFMA.
// Block: (b, co_tile of 128, 2 image rows). 4 waves in 2x2 grid, each wave
// computes 64 co x 64 cols via 4x4 frags of mfma_f32_16x16x32_bf16.
__global__ __launch_bounds__(256) void k_conv(
    const float* __restrict__ x, const unsigned short* __restrict__ dwA,
    float* __restrict__ out)
{
    // x tile: rows r0-1..r0+2 (4), cols -1..64 (66, zero-padded), 32 ci.
    // ci innermost, padded 32->40 (80B stride: 16B-aligned frags, <=2-way banks)
    __shared__ __align__(16) unsigned short xs[4][66][40];

    const int rowgrp  = blockIdx.x;   // 0..31
    const int co_tile = blockIdx.y;   // 0..1
    const int b       = blockIdx.z;   // 0..7
    const int tid  = threadIdx.x;
    const int lane = tid & 63;
    const int wid  = tid >> 6;
    const int wave_m = wid >> 1;      // co half
    const int wave_n = wid & 1;       // row within 2-row tile
    const int quad = lane >> 4;
    const int l16  = lane & 15;
    const int r0 = rowgrp * 2;
    const int co_base = co_tile * 128 + wave_m * 64;

    float4_t acc[4][4];
#pragma unroll
    for (int mi = 0; mi < 4; ++mi)
#pragma unroll
        for (int ni = 0; ni < 4; ++ni)
            acc[mi][ni] = (float4_t){0.f, 0.f, 0.f, 0.f};

    for (int cb = 0; cb < 8; ++cb) {   // ci blocks of 32
        __syncthreads();
        // stage x tile (fp32 -> bf16), 32*4*66 = 8448 elems = 33/thread
#pragma unroll
        for (int it = 0; it < 33; ++it) {
            int idx  = tid + it * 256;
            int ci_l = idx / 264;
            int rem  = idx - ci_l * 264;
            int row  = rem / 66;
            int col  = rem - row * 66;
            int h    = r0 - 1 + row;
            int wimg = col - 1;
            float v = 0.f;
            if ((unsigned)h < 64u && (unsigned)wimg < 64u)
                v = x[(((size_t)b * CIN_ + cb * 32 + ci_l) * 64 + h) * 64 + wimg];
            xs[row][col][ci_l] = f2bf(v);
        }
        __syncthreads();

#pragma unroll
        for (int tap = 0; tap < 9; ++tap) {
            const int dh  = tap / 3;
            const int dwc = tap % 3;

            // A frags: A[m=lane&15][k=quad*8+j], 16B coalesced global loads
            short8_t afrag[4];
            const unsigned short* Ab =
                dwA + ((size_t)(b * 9 + tap) * 32 + (cb * 4 + quad)) * 256 * 8;
#pragma unroll
            for (int mi = 0; mi < 4; ++mi) {
                int co = co_base + mi * 16 + l16;
                afrag[mi] = *(const short8_t*)(Ab + co * 8);
            }

            // B frags: B[k=quad*8+j][n=lane&15] from LDS (ds_read_b128)
            short8_t bfrag[4];
            const int lrow = wave_n + dh;
#pragma unroll
            for (int ni = 0; ni < 4; ++ni) {
                int col = ni * 16 + l16 + dwc;
                bfrag[ni] = *(const short8_t*)&xs[lrow][col][quad * 8];
            }

#pragma unroll
            for (int mi = 0; mi < 4; ++mi)
#pragma unroll
                for (int ni = 0; ni < 4; ++ni)
                    acc[mi][ni] = __builtin_amdgcn_mfma_f32_16x16x32_bf16(
                        afrag[mi], bfrag[ni], acc[mi][ni], 0, 0, 0);
        }
    }

    // epilogue: D row = quad*4 + reg (co), col = lane&15 (img col)
    const int orow = r0 + wave_n;
#pragma unroll
    for (int mi = 0; mi < 4; ++mi) {
#pragma unroll
        for (int ni = 0; ni < 4; ++ni) {
#pragma unroll
            for (int r = 0; r < 4; ++r) {
                int co = co_base + mi * 16 + quad * 4 + r;
                int c  = ni * 16 + l16;
                out[(((size_t)b * COUT_ + co) * 64 + orow) * 64 + c] = acc[mi][ni][r];
            }
        }
    }
}

extern "C" void kernel_launch(void* const* d_in, const int* in_sizes, int n_in,
                              void* d_out, int out_size, void* d_ws, size_t ws_size,
                              hipStream_t stream) {
    const float* x      = (const float*)d_in[0];
    const float* style  = (const float*)d_in[1];
    const float* weight = (const float*)d_in[2];
    float* out = (float*)d_out;
    unsigned short* dwA = (unsigned short*)d_ws;  // 8*9*256*256 bf16 = 9.4 MB

    k_modulate<<<dim3(COUT_, B_), 256, 0, stream>>>(weight, style, dwA);
    k_conv<<<dim3(32, 2, B_), 256, 0, stream>>>(x, dwA, out);
}

// Round 2
// 142.629 us; speedup vs baseline: 1.7939x; 1.7939x over previous
//
#include <hip/hip_runtime.h>

#define B_ 8
#define CIN_ 256
#define COUT_ 256

typedef short short8_t __attribute__((ext_vector_type(8)));
typedef float float4_t __attribute__((ext_vector_type(4)));

// ws layout (bytes): dwA bf16 [0, 9437184) ; xpre bf16 [9437184, 27279360)
#define DWA_SHORTS   (B_ * 9 * 32 * COUT_ * 8)      // 4,718,592
#define XPRE_SHORTS  (B_ * 8 * 66 * 66 * 32)        // 8,921,088

__device__ __forceinline__ unsigned short f2bf(float f) {
    union { float f; unsigned u; } v; v.f = f;
    unsigned u = v.u;
    unsigned r = (u + 0x7fffu + ((u >> 16) & 1u)) >> 16;  // RNE
    return (unsigned short)r;
}

// K1: x fp32 NCHW -> xpre bf16 [b][cb(8)][h(66)][w(66)][ci32], halos pre-zeroed by memset.
__global__ __launch_bounds__(256) void k_xpre(const float* __restrict__ x,
                                              unsigned short* __restrict__ xpre) {
    const int h = blockIdx.x, cb = blockIdx.y, b = blockIdx.z;
    const int t = threadIdx.x;
    const int w = t >> 2, g = t & 3;
    const float* xp = x + (((size_t)(b * CIN_ + cb * 32 + g * 8)) * 64 + h) * 64 + w;
    short8_t v;
#pragma unroll
    for (int j = 0; j < 8; ++j) v[j] = (short)f2bf(xp[(size_t)j * 4096]);
    size_t dst = ((((size_t)(b * 8 + cb)) * 66 + (h + 1)) * 66 + (w + 1)) * 32 + (size_t)g * 8;
    *(short8_t*)(xpre + dst) = v;
}

// K2: modulate+demodulate -> dwA bf16 [b][tap(9)][ci_oct(32)][co(256)][ci8(8)]
// block = (co_grp of 8, b); thread = (co_l = t&7, oct = t>>3)
__global__ __launch_bounds__(256) void k_modulate(const float* __restrict__ weight,
                                                  const float* __restrict__ style,
                                                  unsigned short* __restrict__ dwA) {
    const int b = blockIdx.y;
    const int co = blockIdx.x * 8 + (threadIdx.x & 7);
    const int oct = threadIdx.x >> 3;
    const int lane = threadIdx.x & 63, wid = threadIdx.x >> 6;

    float wreg[72];
    const float* wp = weight + (size_t)co * (CIN_ * 9) + oct * 72;
#pragma unroll
    for (int i = 0; i < 18; ++i)
        *(float4*)(wreg + 4 * i) = *(const float4*)(wp + 4 * i);

    float s[8];
#pragma unroll
    for (int j = 0; j < 8; ++j) s[j] = style[b * CIN_ + oct * 8 + j];

    float part = 0.f;
#pragma unroll
    for (int j = 0; j < 8; ++j) {
        float a = 0.f;
#pragma unroll
        for (int t9 = 0; t9 < 9; ++t9) a += wreg[j * 9 + t9] * wreg[j * 9 + t9];
        part += s[j] * s[j] * a;
    }
    // butterfly over octs within wave (stride 8,16,32), then cross-wave via LDS
    part += __shfl_xor(part, 8, 64);
    part += __shfl_xor(part, 16, 64);
    part += __shfl_xor(part, 32, 64);
    __shared__ float red[4][8];
    if ((lane >> 3) == 0) red[wid][lane & 7] = part;
    __syncthreads();
    const int co_l = threadIdx.x & 7;
    const float tot = red[0][co_l] + red[1][co_l] + red[2][co_l] + red[3][co_l];
    const float inv = 1.0f / sqrtf(tot + 1e-8f);

#pragma unroll
    for (int tap = 0; tap < 9; ++tap) {
        short8_t o;
#pragma unroll
        for (int j = 0; j < 8; ++j) o[j] = (short)f2bf(wreg[j * 9 + tap] * s[j] * inv);
        size_t dst = ((((size_t)(b * 9 + tap)) * 32 + oct) * 256 + co) * 8;
        *(short8_t*)(dwA + dst) = o;
    }
}

// K3: conv as 9 shifted GEMMs, double-buffered LDS + A-frag ping-pong prefetch.
__global__ __launch_bounds__(256) void k_conv(const unsigned short* __restrict__ xpre,
                                              const unsigned short* __restrict__ dwA,
                                              float* __restrict__ out) {
    // per buffer: [4 rows][66 cols][40 (ci pad 32->40, 80B stride)] = 21120B; x2 = 42240B
    __shared__ __align__(16) unsigned short xs[2][4 * 66 * 40];

    const int rowgrp = blockIdx.x;   // 0..31
    const int co_tile = blockIdx.y;  // 0..1
    const int b = blockIdx.z;        // 0..7
    const int tid = threadIdx.x;
    const int lane = tid & 63, wid = tid >> 6;
    const int wave_m = wid >> 1, wave_n = wid & 1;
    const int quad = lane >> 4, l16 = lane & 15;
    const int r0 = rowgrp * 2;
    const int co_base = co_tile * 128 + wave_m * 64;

    float4_t acc[4][4];
#pragma unroll
    for (int mi = 0; mi < 4; ++mi)
#pragma unroll
        for (int ni = 0; ni < 4; ++ni) acc[mi][ni] = (float4_t){0.f, 0.f, 0.f, 0.f};

    // register staging: 1056 chunks of 16B per cb tile (4 rows x 66 cols x 4 ci-groups)
    short8_t st[5];
    auto load_regs = [&](int cb) {
        const unsigned short* s = xpre + ((size_t)((b * 8 + cb) * 66 + r0)) * 2112;
#pragma unroll
        for (int it = 0; it < 4; ++it)
            st[it] = *(const short8_t*)(s + (size_t)(tid + it * 256) * 8);
        if (tid < 32) st[4] = *(const short8_t*)(s + (size_t)(tid + 1024) * 8);
    };
    auto store_lds = [&](int buf) {
        unsigned short* d = xs[buf];
#pragma unroll
        for (int it = 0; it < 4; ++it) {
            int c = tid + it * 256;
            *(short8_t*)(d + (c >> 2) * 40 + (c & 3) * 8) = st[it];
        }
        if (tid < 32) {
            int c = tid + 1024;
            *(short8_t*)(d + (c >> 2) * 40 + (c & 3) * 8) = st[4];
        }
    };

    load_regs(0);

    for (int cb = 0; cb < 8; ++cb) {
        short8_t aA[4], aB[4];
        // A(tap0) issued early: overlaps LDS store + barrier
        {
            const unsigned short* Ab = dwA + ((size_t)(b * 9 + 0) * 32 + cb * 4 + quad) * 2048;
#pragma unroll
            for (int mi = 0; mi < 4; ++mi)
                aA[mi] = *(const short8_t*)(Ab + (co_base + mi * 16 + l16) * 8);
        }
        store_lds(cb & 1);
        __syncthreads();
        if (cb < 7) load_regs(cb + 1);  // in flight during entire compute phase

        const unsigned short* xb = xs[cb & 1];
#pragma unroll
        for (int tap = 0; tap < 9; ++tap) {
            if (tap < 8) {  // prefetch next tap's A into the other bank
                const unsigned short* Ab =
                    dwA + ((size_t)(b * 9 + tap + 1) * 32 + cb * 4 + quad) * 2048;
                short8_t* an = (tap & 1) ? aA : aB;
#pragma unroll
                for (int mi = 0; mi < 4; ++mi)
                    an[mi] = *(const short8_t*)(Ab + (co_base + mi * 16 + l16) * 8);
            }
            const int dh = tap / 3, dwc = tap % 3;
            const unsigned short* brow = xb + (wave_n + dh) * 66 * 40;
            short8_t bf[4];
#pragma unroll
            for (int ni = 0; ni < 4; ++ni)
                bf[ni] = *(const short8_t*)(brow + (ni * 16 + l16 + dwc) * 40 + quad * 8);
            const short8_t* ac = (tap & 1) ? aB : aA;
#pragma unroll
            for (int mi = 0; mi < 4; ++mi)
#pragma unroll
                for (int ni = 0; ni < 4; ++ni)
                    acc[mi][ni] = __builtin_amdgcn_mfma_f32_16x16x32_bf16(
                        ac[mi], bf[ni], acc[mi][ni], 0, 0, 0);
        }
    }

    // epilogue: D row = quad*4 + reg (co), col = lane&15 (img col)
    const int orow = r0 + wave_n;
#pragma unroll
    for (int mi = 0; mi < 4; ++mi)
#pragma unroll
        for (int ni = 0; ni < 4; ++ni)
#pragma unroll
            for (int r = 0; r < 4; ++r) {
                int co = co_base + mi * 16 + quad * 4 + r;
                int c = ni * 16 + l16;
                out[(((size_t)b * COUT_ + co) * 64 + orow) * 64 + c] = acc[mi][ni][r];
            }
}

extern "C" void kernel_launch(void* const* d_in, const int* in_sizes, int n_in,
                              void* d_out, int out_size, void* d_ws, size_t ws_size,
                              hipStream_t stream) {
    const float* x = (const float*)d_in[0];
    const float* style = (const float*)d_in[1];
    const float* weight = (const float*)d_in[2];
    float* out = (float*)d_out;

    unsigned short* dwA = (unsigned short*)d_ws;
    unsigned short* xpre = dwA + DWA_SHORTS;

    // zero xpre (halo padding)
    hipMemsetAsync((void*)xpre, 0, (size_t)XPRE_SHORTS * 2, stream);
    k_xpre<<<dim3(64, 8, B_), 256, 0, stream>>>(x, xpre);
    k_modulate<<<dim3(32, B_), 256, 0, stream>>>(weight, style, dwA);
    k_conv<<<dim3(32, 2, B_), 256, 0, stream>>>(xpre, dwA, out);
}

// Round 3
// 141.839 us; speedup vs baseline: 1.8039x; 1.0056x over previous
//
#include <hip/hip_runtime.h>

#define B_ 8
#define CIN_ 256
#define COUT_ 256

typedef short short8_t __attribute__((ext_vector_type(8)));
typedef float float4_t __attribute__((ext_vector_type(4)));

// ws layout (shorts): dwA [0, DWA_SHORTS) ; xpre [DWA_SHORTS, +XPRE_SHORTS)
#define DWA_SHORTS   (B_ * 9 * 32 * COUT_ * 8)      // 4,718,592
#define XPRE_SHORTS  (B_ * 8 * 66 * 66 * 32)        // 8,921,088

__device__ __forceinline__ unsigned short f2bf(float f) {
    union { float f; unsigned u; } v; v.f = f;
    unsigned u = v.u;
    unsigned r = (u + 0x7fffu + ((u >> 16) & 1u)) >> 16;  // RNE
    return (unsigned short)r;
}

// K1: x fp32 NCHW -> xpre bf16 [b][cb(8)][h66][w66][ci32], halo zeros written here.
__global__ __launch_bounds__(256) void k_xpre(const float* __restrict__ x,
                                              unsigned short* __restrict__ xpre) {
    const int h_out = blockIdx.x;  // 0..65
    const int cb = blockIdx.y, b = blockIdx.z;
    const int t = threadIdx.x;
    const int h_in = h_out - 1;
    unsigned short* dst_row = xpre + (((size_t)(b * 8 + cb) * 66 + h_out)) * 66 * 32;
#pragma unroll
    for (int pass = 0; pass < 2; ++pass) {
        int p = t + pass * 256;
        if (p >= 264) break;
        int w_out = p >> 2, g = p & 3;
        int w_in = w_out - 1;
        short8_t v = (short8_t){0, 0, 0, 0, 0, 0, 0, 0};
        if ((unsigned)h_in < 64u && (unsigned)w_in < 64u) {
            const float* xp = x + (((size_t)(b * CIN_ + cb * 32 + g * 8)) * 64 + h_in) * 64 + w_in;
#pragma unroll
            for (int j = 0; j < 8; ++j) v[j] = (short)f2bf(xp[(size_t)j * 4096]);
        }
        *(short8_t*)(dst_row + (size_t)w_out * 32 + g * 8) = v;
    }
}

// K2: modulate+demodulate -> dwA bf16 [b][tap9][oct32][co256][ci8]
// grid 64 blocks x 256 threads; block handles 4 consecutive co (wave = one co).
__global__ __launch_bounds__(256) void k_modulate(const float* __restrict__ weight,
                                                  const float* __restrict__ style,
                                                  unsigned short* __restrict__ dwA) {
    __shared__ float wlds[4 * 2304];  // 36.9 KB: 4 co's weights
    const int t = threadIdx.x;
    const int co0 = blockIdx.x * 4;
    const int co_l = t >> 6;          // wave id = local co
    const int lane = t & 63;
    const int co = co0 + co_l;

    // coalesced cooperative load of 4*2304 = 9216 floats
    const float* wp = weight + (size_t)co0 * 2304;
#pragma unroll
    for (int k = 0; k < 36; ++k) wlds[t + 256 * k] = wp[t + 256 * k];
    __syncthreads();

    // each lane owns ci = lane + 64k, k=0..3
    float wv[4][9];
    float ss[4];
#pragma unroll
    for (int k = 0; k < 4; ++k) {
        float a = 0.f;
#pragma unroll
        for (int tap = 0; tap < 9; ++tap) {
            float w = wlds[co_l * 2304 + (lane + 64 * k) * 9 + tap];
            wv[k][tap] = w;
            a += w * w;
        }
        ss[k] = a;
    }
    float sv[8][4];
#pragma unroll
    for (int b = 0; b < 8; ++b)
#pragma unroll
        for (int k = 0; k < 4; ++k) sv[b][k] = style[b * CIN_ + lane + 64 * k];

    float inv[8];
#pragma unroll
    for (int b = 0; b < 8; ++b) {
        float part = 0.f;
#pragma unroll
        for (int k = 0; k < 4; ++k) part += sv[b][k] * sv[b][k] * ss[k];
#pragma unroll
        for (int off = 32; off > 0; off >>= 1) part += __shfl_xor(part, off, 64);
        inv[b] = 1.0f / sqrtf(part + 1e-8f);
    }

    // writes: 2B/lane; lanes 0-7 contiguous (16B); 4 waves of the block fill full
    // 64B lines (same CU/XCD -> L2 merges, no write amplification)
    const size_t base = (size_t)co * 8 + (lane & 7) + (size_t)(lane >> 3) * 2048;
#pragma unroll
    for (int b = 0; b < 8; ++b)
#pragma unroll
        for (int tap = 0; tap < 9; ++tap)
#pragma unroll
            for (int k = 0; k < 4; ++k) {
                size_t addr = ((size_t)(b * 9 + tap) * 32 + k * 8) * 2048 + base;
                dwA[addr] = f2bf(wv[k][tap] * sv[b][k] * inv[b]);
            }
}

// K3: conv as 9 shifted GEMMs; double-buffered LDS x-tile + 3-deep A-frag rotation.
__global__ __launch_bounds__(256) void k_conv(const unsigned short* __restrict__ xpre,
                                              const unsigned short* __restrict__ dwA,
                                              float* __restrict__ out) {
    __shared__ __align__(16) unsigned short xs[2][4 * 66 * 40];  // 42.2 KB

    const int rowgrp = blockIdx.x;   // 0..31
    const int co_tile = blockIdx.y;  // 0..1
    const int b = blockIdx.z;        // 0..7
    const int tid = threadIdx.x;
    const int lane = tid & 63, wid = tid >> 6;
    const int wave_m = wid >> 1, wave_n = wid & 1;
    const int quad = lane >> 4, l16 = lane & 15;
    const int r0 = rowgrp * 2;
    const int co_base = co_tile * 128 + wave_m * 64;

    float4_t acc[4][4];
#pragma unroll
    for (int mi = 0; mi < 4; ++mi)
#pragma unroll
        for (int ni = 0; ni < 4; ++ni) acc[mi][ni] = (float4_t){0.f, 0.f, 0.f, 0.f};

    short8_t st[5];
    auto load_regs = [&](int cb) {
        const unsigned short* s = xpre + ((size_t)((b * 8 + cb) * 66 + r0)) * 2112;
#pragma unroll
        for (int it = 0; it < 4; ++it)
            st[it] = *(const short8_t*)(s + (size_t)(tid + it * 256) * 8);
        if (tid < 32) st[4] = *(const short8_t*)(s + (size_t)(tid + 1024) * 8);
    };
    auto store_lds = [&](int buf) {
        unsigned short* d = xs[buf];
#pragma unroll
        for (int it = 0; it < 4; ++it) {
            int c = tid + it * 256;
            *(short8_t*)(d + (c >> 2) * 40 + (c & 3) * 8) = st[it];
        }
        if (tid < 32) {
            int c = tid + 1024;
            *(short8_t*)(d + (c >> 2) * 40 + (c & 3) * 8) = st[4];
        }
    };

    short8_t abuf[3][4];
    auto loadA = [&](short8_t* dst, int acb, int atap) {
        const unsigned short* Ab = dwA + ((size_t)(b * 9 + atap) * 32 + acb * 4 + quad) * 2048;
#pragma unroll
        for (int mi = 0; mi < 4; ++mi)
            dst[mi] = *(const short8_t*)(Ab + (co_base + mi * 16 + l16) * 8);
    };

    load_regs(0);
    loadA(abuf[0], 0, 0);
    loadA(abuf[1], 0, 1);

    for (int cb = 0; cb < 8; ++cb) {
        store_lds(cb & 1);
        __syncthreads();
        if (cb < 7) load_regs(cb + 1);

        const unsigned short* xb = xs[cb & 1];
#pragma unroll
        for (int tap = 0; tap < 9; ++tap) {
            // prefetch A two steps ahead (linearized across cb boundary)
            const int nl = tap + 2;
            const int acb = cb + nl / 9, atap = nl % 9;
            if (acb < 8) loadA(abuf[nl % 3], acb, atap);

            const int dh = tap / 3, dwc = tap % 3;
            const unsigned short* brow = xb + (wave_n + dh) * 66 * 40;
            short8_t bf[4];
#pragma unroll
            for (int ni = 0; ni < 4; ++ni)
                bf[ni] = *(const short8_t*)(brow + (ni * 16 + l16 + dwc) * 40 + quad * 8);

            const short8_t* ac = abuf[tap % 3];
#pragma unroll
            for (int mi = 0; mi < 4; ++mi)
#pragma unroll
                for (int ni = 0; ni < 4; ++ni)
                    acc[mi][ni] = __builtin_amdgcn_mfma_f32_16x16x32_bf16(
                        ac[mi], bf[ni], acc[mi][ni], 0, 0, 0);
        }
    }

    // epilogue: D row = quad*4 + reg (co), col = lane&15 (img col)
    const int orow = r0 + wave_n;
#pragma unroll
    for (int mi = 0; mi < 4; ++mi)
#pragma unroll
        for (int ni = 0; ni < 4; ++ni)
#pragma unroll
            for (int r = 0; r < 4; ++r) {
                int co = co_base + mi * 16 + quad * 4 + r;
                int c = ni * 16 + l16;
                out[(((size_t)b * COUT_ + co) * 64 + orow) * 64 + c] = acc[mi][ni][r];
            }
}

extern "C" void kernel_launch(void* const* d_in, const int* in_sizes, int n_in,
                              void* d_out, int out_size, void* d_ws, size_t ws_size,
                              hipStream_t stream) {
    const float* x = (const float*)d_in[0];
    const float* style = (const float*)d_in[1];
    const float* weight = (const float*)d_in[2];
    float* out = (float*)d_out;

    unsigned short* dwA = (unsigned short*)d_ws;
    unsigned short* xpre = dwA + DWA_SHORTS;

    k_xpre<<<dim3(66, 8, B_), 256, 0, stream>>>(x, xpre);
    k_modulate<<<dim3(64), 256, 0, stream>>>(weight, style, dwA);
    k_conv<<<dim3(32, 2, B_), 256, 0, stream>>>(xpre, dwA, out);
}